// Round 4
// baseline (97.991 us; speedup 1.0000x reference)
//
#include <hip/hip_runtime.h>
#include <hip/hip_bf16.h>

typedef __bf16 bf16_t;
typedef bf16_t bf16x8 __attribute__((ext_vector_type(8)));
typedef float  floatx4 __attribute__((ext_vector_type(4)));

#define NROWS 65536
#define NCENT 512
#define NDIM  128
#define TROWS 64
#define TPB   4
#define NBLK  (NROWS / (TROWS * TPB))   // 256 blocks x 1024 thr = exactly 1 block/CU

// Single fused kernel, no workspace.
//  - 16 waves; wave w owns centroids [w*32, w*32+32): bfr[2][4] = 32 VGPRs/lane.
//    Total VGPR budget ~82 << 128 cap of (1024,4): no spill by construction.
//  - mu loaded fp32->bf16 in-register (L2-resident); h2 = 0.5|mu_bf16|^2 via quad shuffles.
//  - z tile (64x128 fp32) reg-staged: thread c=(s,kk,q,r16) reads 32B at
//    row=s*16+r16, k=kk*32+q*8 (global: full 128B/row rectangles); writes one
//    contiguous bf16x8 to frag-major LDS elem s*2048+kk*512+q*128+r16*8
//    (quarter-wave lanes r16=0..15 -> 256B contiguous: conflict-free).
//  - A-frag reads: afr[kk] at s*2048+kk*512+quad*128+l16*8 (contiguous/quarter-wave).
//  - z2 (rounded-z |.|^2) computed per strip s by wave w==s from its A-frags.
//  - double-buffered zt, loads for tile t+1 issued before tile t's MFMA phase.

__global__ __launch_bounds__(1024, 4)
void kmeans_fused(const float* __restrict__ z, const float* __restrict__ mu,
                  float* __restrict__ out)
{
    __shared__ bf16_t zt[2][TROWS * NDIM];   // 2 x 16 KB
    __shared__ float  z2s[TROWS];            // 256 B
    __shared__ float  rmx[16][TROWS];        // 4 KB   -> 37.1 KB total

    const int tid  = threadIdx.x;
    const int lane = tid & 63;
    const int w    = tid >> 6;        // wave 0..15
    const int quad = lane >> 4;
    const int l16  = lane & 15;

    // staging map for this thread (c = tid): global 32B <-> LDS 16B frag chunk
    const int c_s   = tid >> 8;          // strip 0..3
    const int c_kk  = (tid >> 6) & 3;
    const int c_q   = (tid >> 4) & 3;
    const int c_r16 = tid & 15;
    const int g_off = (c_s * 16 + c_r16) * NDIM + c_kk * 32 + c_q * 8;   // float idx in tile
    const int l_off = c_s * 2048 + c_kk * 512 + c_q * 128 + c_r16 * 8;   // bf16 idx in tile

    const size_t zb0 = (size_t)blockIdx.x * TPB * TROWS * NDIM;

    // ---- issue tile-0 z loads first; they fly under the mu prologue ----
    float4 a0 = *(const float4*)(z + zb0 + g_off);
    float4 a1 = *(const float4*)(z + zb0 + g_off + 4);

    // ---- persistent B fragments (32 VGPRs) + h2, straight from fp32 mu ----
    bf16x8 bfr[2][4];
    float  h2r[2];
#pragma unroll
    for (int g = 0; g < 2; ++g) {
        const int col = w * 32 + g * 16 + l16;
#pragma unroll
        for (int kk = 0; kk < 4; ++kk) {
            const float* mp = mu + col * NDIM + kk * 32 + quad * 8;
            const float4 x = *(const float4*)(mp);
            const float4 y = *(const float4*)(mp + 4);
            bfr[g][kk] = (bf16x8){(bf16_t)x.x, (bf16_t)x.y, (bf16_t)x.z, (bf16_t)x.w,
                                  (bf16_t)y.x, (bf16_t)y.y, (bf16_t)y.z, (bf16_t)y.w};
        }
        float ss = 0.f;
#pragma unroll
        for (int kk = 0; kk < 4; ++kk)
#pragma unroll
            for (int e = 0; e < 8; ++e) { float f = (float)bfr[g][kk][e]; ss = fmaf(f, f, ss); }
        ss += __shfl_xor(ss, 16);   // reduce over the 4 quads (k-chunks) of this col
        ss += __shfl_xor(ss, 32);
        h2r[g] = 0.5f * ss;
    }

    // ---- finish tile-0 staging: cvt + one contiguous ds_write_b128 ----
    {
        bf16x8 pk = {(bf16_t)a0.x, (bf16_t)a0.y, (bf16_t)a0.z, (bf16_t)a0.w,
                     (bf16_t)a1.x, (bf16_t)a1.y, (bf16_t)a1.z, (bf16_t)a1.w};
        *(bf16x8*)&zt[0][l_off] = pk;
    }
    __syncthreads();   // tile 0 resident

    float fsum = 0.f;

    for (int t = 0; t < TPB; ++t) {
        const int cur = t & 1;

        // issue next-tile global loads; latency hides under the MFMA phase
        if (t + 1 < TPB) {
            const float* zp = z + zb0 + (size_t)(t + 1) * TROWS * NDIM + g_off;
            a0 = *(const float4*)(zp);
            a1 = *(const float4*)(zp + 4);
        }

        // ---- compute: 4 strips x (2 colgroups x 4 MFMA) ----
#pragma unroll
        for (int s = 0; s < 4; ++s) {
            bf16x8 afr[4];
#pragma unroll
            for (int kk = 0; kk < 4; ++kk)
                afr[kk] = *(const bf16x8*)&zt[cur][s * 2048 + kk * 512 + quad * 128 + l16 * 8];

            if (w == s) {   // z2 of rounded z for strip s (wave s only; uniform branch)
                float ss = 0.f;
#pragma unroll
                for (int kk = 0; kk < 4; ++kk)
#pragma unroll
                    for (int e = 0; e < 8; ++e) { float f = (float)afr[kk][e]; ss = fmaf(f, f, ss); }
                ss += __shfl_xor(ss, 16);
                ss += __shfl_xor(ss, 32);
                if (lane < 16) z2s[s * 16 + lane] = ss;
            }

            float vm[4] = {-3.0e38f, -3.0e38f, -3.0e38f, -3.0e38f};
#pragma unroll
            for (int g = 0; g < 2; ++g) {
                floatx4 acc = (floatx4){0.f, 0.f, 0.f, 0.f};
#pragma unroll
                for (int kk = 0; kk < 4; ++kk)
                    acc = __builtin_amdgcn_mfma_f32_16x16x32_bf16(afr[kk], bfr[g][kk], acc, 0, 0, 0);
#pragma unroll
                for (int r = 0; r < 4; ++r)
                    vm[r] = fmaxf(vm[r], acc[r] - h2r[g]);   // deferred-sqrt: max(dot - m2/2)
            }
#pragma unroll
            for (int r = 0; r < 4; ++r) {                    // max over this wave's 16 cols
                float v = vm[r];
                v = fmaxf(v, __shfl_xor(v, 1));
                v = fmaxf(v, __shfl_xor(v, 2));
                v = fmaxf(v, __shfl_xor(v, 4));
                v = fmaxf(v, __shfl_xor(v, 8));
                if (l16 == 0) rmx[w][s * 16 + quad * 4 + r] = v;
            }
        }
        __syncthreads();   // B1: rmx/z2s visible; zt[cur] reads complete

        // ---- stage tile t+1 into the other buffer (writes zt[cur^1]) ----
        if (t + 1 < TPB) {
            bf16x8 pk = {(bf16_t)a0.x, (bf16_t)a0.y, (bf16_t)a0.z, (bf16_t)a0.w,
                         (bf16_t)a1.x, (bf16_t)a1.y, (bf16_t)a1.z, (bf16_t)a1.w};
            *(bf16x8*)&zt[cur ^ 1][l_off] = pk;
        }
        // ---- row epilogue: max over 16 waves, one sqrt per row ----
        if (tid < TROWS) {
            float m = rmx[0][tid];
#pragma unroll
            for (int jj = 1; jj < 16; ++jj) m = fmaxf(m, rmx[jj][tid]);
            float d2 = z2s[tid] - 2.0f * m;
            fsum += sqrtf(fmaxf(d2, 0.f));
        }
        __syncthreads();   // B2: zt[cur^1] ready; rmx/z2s free for next tile
    }

    // ---- wave 0 holds all row sums; reduce + one atomic per block ----
    if (w == 0) {
        float v = fsum;
#pragma unroll
        for (int off = 32; off; off >>= 1) v += __shfl_down(v, off);
        if (tid == 0) atomicAdd(out, v * (1.0f / 65536.0f));
    }
}

extern "C" void kernel_launch(void* const* d_in, const int* in_sizes, int n_in,
                              void* d_out, int out_size, void* d_ws, size_t ws_size,
                              hipStream_t stream) {
    const float* z  = (const float*)d_in[0];
    const float* mu = (const float*)d_in[1];
    float* out = (float*)d_out;
    hipMemsetAsync(out, 0, sizeof(float), stream);   // d_out is poisoned 0xAA
    kmeans_fused<<<dim3(NBLK), dim3(1024), 0, stream>>>(z, mu, out);
}

// Round 5
// 93.021 us; speedup vs baseline: 1.0534x; 1.0534x over previous
//
#include <hip/hip_runtime.h>
#include <hip/hip_bf16.h>

typedef __bf16 bf16_t;
typedef bf16_t bf16x8 __attribute__((ext_vector_type(8)));
typedef bf16_t bf16x4 __attribute__((ext_vector_type(4)));
typedef float  floatx4 __attribute__((ext_vector_type(4)));

#define NROWS 65536
#define NCENT 512
#define NDIM  128
#define TROWS 64
#define TPB   4
#define NBLK  (NROWS / (TROWS * TPB))   // 256 blocks x 1024 thr = 1 block/CU

// ws: [0,131072) mu bf16 frag-major  addr = (col>>4)*2048 + kk*512 + quad*128 + (col&15)*8
//     [131072,133120) h2 = 0.5*|mu_bf16|^2 float[512]

__global__ __launch_bounds__(256)
void mu_pack_kernel(const float* __restrict__ mu, bf16_t* __restrict__ ws_mu,
                    float* __restrict__ ws_h2, float* __restrict__ out)
{
    const int tid = threadIdx.x;
    if (blockIdx.x == 0 && tid == 0) *out = 0.f;   // replaces the memset dispatch
    const int col_local = tid >> 5;     // 8 cols per block
    const int j = tid & 31;             // 32 threads per col, 4 floats each
    const int col = blockIdx.x * 8 + col_local;
    const float4 v = *(const float4*)(mu + col * NDIM + j * 4);
    bf16x4 pk = {(bf16_t)v.x, (bf16_t)v.y, (bf16_t)v.z, (bf16_t)v.w};
    const int k0 = j * 4;
    const int kk = k0 >> 5, quad = (k0 >> 3) & 3, e0 = k0 & 7;
    const int addr = (col >> 4) * 2048 + kk * 512 + quad * 128 + (col & 15) * 8 + e0;
    *(bf16x4*)(ws_mu + addr) = pk;
    float f0 = (float)pk[0], f1 = (float)pk[1], f2 = (float)pk[2], f3 = (float)pk[3];
    float s = f0 * f0 + f1 * f1 + f2 * f2 + f3 * f3;
    s += __shfl_xor(s, 1);  s += __shfl_xor(s, 2);  s += __shfl_xor(s, 4);
    s += __shfl_xor(s, 8);  s += __shfl_xor(s, 16);
    if (j == 0) ws_h2[col] = 0.5f * s;
}

// main: R4's body, but B fragments come from pre-packed bf16 (no fp32-mu
// prologue / cvt chains). 16 waves x 32 cols; bfr[2][4] = 32 VGPR; est ~87 total.
__global__ __launch_bounds__(1024, 4)
void kmeans_main(const float* __restrict__ z, const bf16_t* __restrict__ wmu,
                 const float* __restrict__ wh2, float* __restrict__ out)
{
    __shared__ bf16_t zt[2][TROWS * NDIM];   // 2 x 16 KB
    __shared__ float  z2s[TROWS];            // 256 B
    __shared__ float  rmx[16][TROWS];        // 4 KB   -> 37.1 KB total

    const int tid  = threadIdx.x;
    const int lane = tid & 63;
    const int w    = tid >> 6;        // wave 0..15; owns cols [w*32, w*32+32)
    const int quad = lane >> 4;
    const int l16  = lane & 15;

    // staging map: thread (s,kk,q,r16) <-> 32B global rect / 16B LDS frag chunk
    const int c_s   = tid >> 8;
    const int c_kk  = (tid >> 6) & 3;
    const int c_q   = (tid >> 4) & 3;
    const int c_r16 = tid & 15;
    const int g_off = (c_s * 16 + c_r16) * NDIM + c_kk * 32 + c_q * 8;   // float idx
    const int l_off = c_s * 2048 + c_kk * 512 + c_q * 128 + c_r16 * 8;   // bf16 idx

    const size_t zb0 = (size_t)blockIdx.x * TPB * TROWS * NDIM;

    // ---- issue tile-0 z loads first ----
    float4 a0 = *(const float4*)(z + zb0 + g_off);
    float4 a1 = *(const float4*)(z + zb0 + g_off + 4);

    // ---- persistent B fragments from packed bf16: 8 x 16B contiguous loads ----
    bf16x8 bfr[2][4];
    float  h2r[2];
#pragma unroll
    for (int g = 0; g < 2; ++g) {
        const int j = w * 2 + g;   // col group; col = j*16 + l16
#pragma unroll
        for (int kk = 0; kk < 4; ++kk)
            bfr[g][kk] = *(const bf16x8*)(wmu + j * 2048 + kk * 512 + quad * 128 + l16 * 8);
        h2r[g] = wh2[j * 16 + l16];
    }

    // ---- finish tile-0 staging: cvt + one contiguous ds_write_b128 ----
    {
        bf16x8 pk = {(bf16_t)a0.x, (bf16_t)a0.y, (bf16_t)a0.z, (bf16_t)a0.w,
                     (bf16_t)a1.x, (bf16_t)a1.y, (bf16_t)a1.z, (bf16_t)a1.w};
        *(bf16x8*)&zt[0][l_off] = pk;
    }
    __syncthreads();   // tile 0 resident

    float fsum = 0.f;

    for (int t = 0; t < TPB; ++t) {
        const int cur = t & 1;

        // next-tile global loads; latency hides under this tile's MFMA phase
        if (t + 1 < TPB) {
            const float* zp = z + zb0 + (size_t)(t + 1) * TROWS * NDIM + g_off;
            a0 = *(const float4*)(zp);
            a1 = *(const float4*)(zp + 4);
        }

        // ---- compute: 4 strips x (2 colgroups x 4 MFMA) ----
#pragma unroll
        for (int s = 0; s < 4; ++s) {
            bf16x8 afr[4];
#pragma unroll
            for (int kk = 0; kk < 4; ++kk)
                afr[kk] = *(const bf16x8*)&zt[cur][s * 2048 + kk * 512 + quad * 128 + l16 * 8];

            if (w == s) {   // z2 of rounded z for strip s (uniform branch, 1 wave)
                float ss = 0.f;
#pragma unroll
                for (int kk = 0; kk < 4; ++kk)
#pragma unroll
                    for (int e = 0; e < 8; ++e) { float f = (float)afr[kk][e]; ss = fmaf(f, f, ss); }
                ss += __shfl_xor(ss, 16);
                ss += __shfl_xor(ss, 32);
                if (lane < 16) z2s[s * 16 + lane] = ss;
            }

            float vm[4] = {-3.0e38f, -3.0e38f, -3.0e38f, -3.0e38f};
#pragma unroll
            for (int g = 0; g < 2; ++g) {
                floatx4 acc = (floatx4){0.f, 0.f, 0.f, 0.f};
#pragma unroll
                for (int kk = 0; kk < 4; ++kk)
                    acc = __builtin_amdgcn_mfma_f32_16x16x32_bf16(afr[kk], bfr[g][kk], acc, 0, 0, 0);
#pragma unroll
                for (int r = 0; r < 4; ++r)
                    vm[r] = fmaxf(vm[r], acc[r] - h2r[g]);   // deferred-sqrt: max(dot - m2/2)
            }
#pragma unroll
            for (int r = 0; r < 4; ++r) {                    // max over this wave's 16 cols
                float v = vm[r];
                v = fmaxf(v, __shfl_xor(v, 1));
                v = fmaxf(v, __shfl_xor(v, 2));
                v = fmaxf(v, __shfl_xor(v, 4));
                v = fmaxf(v, __shfl_xor(v, 8));
                if (l16 == 0) rmx[w][s * 16 + quad * 4 + r] = v;
            }
        }
        __syncthreads();   // B1: rmx/z2s visible; zt[cur] reads complete

        // ---- stage tile t+1 into the other buffer ----
        if (t + 1 < TPB) {
            bf16x8 pk = {(bf16_t)a0.x, (bf16_t)a0.y, (bf16_t)a0.z, (bf16_t)a0.w,
                         (bf16_t)a1.x, (bf16_t)a1.y, (bf16_t)a1.z, (bf16_t)a1.w};
            *(bf16x8*)&zt[cur ^ 1][l_off] = pk;
        }
        // ---- row epilogue: max over 16 waves, one sqrt per row ----
        if (tid < TROWS) {
            float m = rmx[0][tid];
#pragma unroll
            for (int jj = 1; jj < 16; ++jj) m = fmaxf(m, rmx[jj][tid]);
            float d2 = z2s[tid] - 2.0f * m;
            fsum += sqrtf(fmaxf(d2, 0.f));
        }
        __syncthreads();   // B2: zt[cur^1] ready; rmx/z2s free for next tile
    }

    // ---- wave 0 holds all row sums; reduce + one atomic per block ----
    if (w == 0) {
        float v = fsum;
#pragma unroll
        for (int off = 32; off; off >>= 1) v += __shfl_down(v, off);
        if (tid == 0) atomicAdd(out, v * (1.0f / 65536.0f));
    }
}

extern "C" void kernel_launch(void* const* d_in, const int* in_sizes, int n_in,
                              void* d_out, int out_size, void* d_ws, size_t ws_size,
                              hipStream_t stream) {
    const float* z  = (const float*)d_in[0];
    const float* mu = (const float*)d_in[1];
    float* out = (float*)d_out;
    bf16_t* ws_mu = (bf16_t*)d_ws;
    float*  ws_h2 = (float*)((char*)d_ws + 131072);
    mu_pack_kernel<<<dim3(64),   dim3(256),  0, stream>>>(mu, ws_mu, ws_h2, out);
    kmeans_main   <<<dim3(NBLK), dim3(1024), 0, stream>>>(z, ws_mu, ws_h2, out);
}